// Round 4
// baseline (531.372 us; speedup 1.0000x reference)
//
#include <hip/hip_runtime.h>

// CompositionalEmbedding on MI355X — round 6 (measurement round; source == round 4/5).
// Standing theory: k_main is latency/occupancy-bound (490 µs measured at r2 vs
// ~80 µs store floor). Bets in flight, statically re-verified twice:
//   - occupancy 2 -> 4 blocks/CU (__launch_bounds__(256,4), VGPR <= 128, no spill
//     by hand count: Phase A and Phase B register peaks are disjoint, ~110 max)
//   - Phase A: row-streamed softmax, no max-subtract (|s| <~ 0.1 by construction),
//     1/sqrt(32) folded into D/E/F/G, bias row folded via sumw==1 (exact)
//   - Phase B: mh-outer (afrag = 32 VGPRs, W2 re-read 2x from L2)
//   - out stores nontemporal (402 MB write-once stream; protect L2 tables)

typedef __attribute__((ext_vector_type(8))) short bf16x8;
typedef __attribute__((ext_vector_type(4))) float floatx4;

__device__ __forceinline__ unsigned short f32_bf16(float f) {
  unsigned int x = __float_as_uint(f);
  x += 0x7FFFu + ((x >> 16) & 1u);   // RNE
  return (unsigned short)(x >> 16);
}

// ---------------- P1: proj[142][384] = {table rows, val_w, val_b} @ in_proj_w^T
__global__ void k_proj_tables(const float* __restrict__ dev_t, const float* __restrict__ pse_t,
                              const float* __restrict__ att_t, const float* __restrict__ unt_t,
                              const float* __restrict__ val_w, const float* __restrict__ val_b,
                              const float* __restrict__ W /*[384][128]*/,
                              float* __restrict__ out /*[142][384]*/) {
  __shared__ float src[128];
  int r = blockIdx.x;
  const float* s;
  if (r < 10)        s = dev_t + r * 128;
  else if (r < 20)   s = pse_t + (r - 10) * 128;
  else if (r < 120)  s = att_t + (r - 20) * 128;
  else if (r < 140)  s = unt_t + (r - 120) * 128;
  else if (r == 140) s = val_w;           // [128][1] contiguous
  else               s = val_b;
  int t = threadIdx.x;                    // 384 threads
  if (t < 128) src[t] = s[t];
  __syncthreads();
  const float* wr = W + t * 128;
  float acc = 0.f;
#pragma unroll 8
  for (int e = 0; e < 128; ++e) acc = fmaf(wr[e], src[e], acc);
  out[r * 384 + t] = acc;
}

// ---------------- P2: W2[768][128] bf16 = out_w @ out_proj_w ; b2 = out_w@out_proj_b + out_b
__global__ void k_fuse_w2(const float* __restrict__ out_w /*[768][128]*/,
                          const float* __restrict__ opw /*[128][128]*/,
                          const float* __restrict__ opb /*[128]*/,
                          const float* __restrict__ out_b /*[768]*/,
                          unsigned short* __restrict__ W2 /*[768][128] bf16*/,
                          float* __restrict__ b2 /*[768]*/) {
  __shared__ float row[128];
  __shared__ float red[128];
  int r = blockIdx.x, c = threadIdx.x;    // 128 threads
  row[c] = out_w[r * 128 + c];
  __syncthreads();
  float acc = 0.f;
#pragma unroll 8
  for (int k = 0; k < 128; ++k) acc = fmaf(row[k], opw[k * 128 + c], acc);
  W2[r * 128 + c] = f32_bf16(acc);
  red[c] = row[c] * opb[c];
  __syncthreads();
#pragma unroll
  for (int s = 64; s > 0; s >>= 1) {
    if (c < s) red[c] += red[c + s];
    __syncthreads();
  }
  if (c == 0) b2[r] = red[0] + out_b[r];
}

// ---------------- P3: score dot tables (PRE-SCALED by 1/sqrt(32)) + bf16 V table
// D[q][k][h] = SC * (q-slice proj[q], head h) . (k-slice proj[k], head h)
// E[q][h] = SC * Pq_q . bk ; F[k][h] = SC * bq . Pk_k ; G[h] = SC * bq . bk
// PvB[row][dc][h][8] bf16; row 142 = v-slice of bias (NOT scaled — it's V data).
__global__ void k_dots(const float* __restrict__ proj, const float* __restrict__ bias,
                       float* __restrict__ D, float* __restrict__ E,
                       float* __restrict__ F, float* __restrict__ G,
                       unsigned short* __restrict__ PvB) {
  const float SC = 0.17677669529663687f;  // 1/sqrt(32)
  __shared__ float qs[128];
  const int q = blockIdx.x;     // 0..141
  const int t = threadIdx.x;    // 256
  if (t < 128) qs[t] = proj[q * 384 + t];
  __syncthreads();
  for (int o = t; o < 568; o += 256) {
    const int k = o >> 2, h = o & 3;
    const float* kp = proj + k * 384 + 128 + h * 32;
    const float* qp = qs + h * 32;
    float acc = 0.f;
#pragma unroll
    for (int d = 0; d < 32; ++d) acc = fmaf(qp[d], kp[d], acc);
    D[(size_t)(q * 142 + k) * 4 + h] = acc * SC;
  }
  if (t < 4) {
    const int h = t;
    float e = 0.f, f = 0.f;
#pragma unroll
    for (int d = 0; d < 32; ++d) {
      e = fmaf(qs[h * 32 + d], bias[128 + h * 32 + d], e);
      f = fmaf(bias[h * 32 + d], proj[q * 384 + 128 + h * 32 + d], f);
    }
    E[q * 4 + h] = e * SC;
    F[q * 4 + h] = f * SC;
    if (q == 0) {
      float g = 0.f;
#pragma unroll
      for (int d = 0; d < 32; ++d) g = fmaf(bias[h * 32 + d], bias[128 + h * 32 + d], g);
      G[h] = g * SC;
    }
  }
  if (t >= 128) {
    const int x = t - 128;                       // 0..127, col in v-slice
    const int h = x >> 5, dc = (x >> 3) & 3, j = x & 7;
    PvB[q * 128 + dc * 32 + h * 8 + j] = f32_bf16(proj[q * 384 + 256 + x]);
    if (q == 0) PvB[142 * 128 + dc * 32 + h * 8 + j] = f32_bf16(bias[256 + x]);
  }
}

// ---------------- main: 64 rows/block, 256 threads
#define LDS_STRIDE 136   // bf16 elems/row: 272 B; row-stride 4 banks -> conflict-neutral b128

__device__ __forceinline__ void unpack8(float d[8], uint4 p) {
  d[0] = __uint_as_float(p.x << 16); d[1] = __uint_as_float(p.x & 0xffff0000u);
  d[2] = __uint_as_float(p.y << 16); d[3] = __uint_as_float(p.y & 0xffff0000u);
  d[4] = __uint_as_float(p.z << 16); d[5] = __uint_as_float(p.z & 0xffff0000u);
  d[6] = __uint_as_float(p.w << 16); d[7] = __uint_as_float(p.w & 0xffff0000u);
}

__device__ __forceinline__ void sm_accum(const float r[5], float w5[5]) {
  // scores pre-scaled; |s| << 88 so exp without max-shift is safe
  float e0 = __expf(r[0]), e1 = __expf(r[1]), e2 = __expf(r[2]),
        e3 = __expf(r[3]), e4 = __expf(r[4]);
  const float inv = 0.2f / (e0 + e1 + e2 + e3 + e4);   // mean over q folded in
  w5[0] = fmaf(e0, inv, w5[0]); w5[1] = fmaf(e1, inv, w5[1]);
  w5[2] = fmaf(e2, inv, w5[2]); w5[3] = fmaf(e3, inv, w5[3]);
  w5[4] = fmaf(e4, inv, w5[4]);
}

__global__ __launch_bounds__(256, 4)   // 4 blocks/CU: the round's bet (<=128 VGPR)
void k_main(const int* __restrict__ dev_ids, const int* __restrict__ pse_ids,
            const int* __restrict__ att_ids, const int* __restrict__ unt_ids,
            const float* __restrict__ values, const int* __restrict__ mask,
            const float* __restrict__ D, const float* __restrict__ E,
            const float* __restrict__ F, const float* __restrict__ G,
            const unsigned short* __restrict__ PvB,
            const unsigned short* __restrict__ W2 /*[768][128] bf16*/,
            const float* __restrict__ b2 /*[768]*/,
            float* __restrict__ out /*[N][768]*/) {
  __shared__ __align__(16) unsigned short sMean[64 * LDS_STRIDE];

  const int tid = threadIdx.x;
  const int lr = tid >> 2;        // local row 0..63
  const int h  = tid & 3;         // head 0..3 (adjacent lanes = 4 heads -> 16B coalesced gathers)
  const int n  = blockIdx.x * 64 + lr;

  // ---- Phase A: scores from precomputed (pre-scaled) dots, weighted V combine ----
  {
    int R[4];
    R[0] = dev_ids[n];
    R[1] = 10 + pse_ids[n];
    R[2] = 20 + att_ids[n];
    R[3] = 120 + unt_ids[n];
    const float val = values[n];
    float m[5];
#pragma unroll
    for (int t = 0; t < 5; ++t) m[t] = (float)mask[n * 5 + t];
    const float mi[4] = {m[0], m[1], m[2], m[4]};
    const float m3 = m[3];

    // gathers; fold val into the (w,b) pairs immediately to cut live regs
    float Dqk[4][4], Dqv[4], Dvk[4], Eq[4], Fk[4];
#pragma unroll
    for (int i = 0; i < 4; ++i) {
      const size_t ri = (size_t)R[i] * 568 + h;   // (q*142+k)*4+h with k folded below
#pragma unroll
      for (int j = 0; j < 4; ++j)
        Dqk[i][j] = D[ri + R[j] * 4];
      Dqv[i] = fmaf(val, D[ri + 560], D[ri + 564]);                 // k=140,141
      Dvk[i] = fmaf(val, D[(size_t)79520 + R[i] * 4 + h],           // q=140
                         D[(size_t)80088 + R[i] * 4 + h]);          // q=141
      Eq[i]  = E[R[i] * 4 + h];
      Fk[i]  = F[R[i] * 4 + h];
    }
    const float E3  = fmaf(val, E[560 + h], E[564 + h]);
    const float F3  = fmaf(val, F[560 + h], F[564 + h]);
    const float D33 = fmaf(val * val, D[80080 + h],
                      fmaf(val, D[80084 + h] + D[80648 + h], D[80652 + h]));
    const float Gh  = G[h];

    // row-streamed softmax: one 5-score row live at a time
    const int ti[4] = {0, 1, 2, 4};
    float w5[5] = {0.f, 0.f, 0.f, 0.f, 0.f};
    {
      float r[5];
#pragma unroll
      for (int i = 0; i < 4; ++i) {
        const float base = fmaf(mi[i], Eq[i], Gh);
#pragma unroll
        for (int j = 0; j < 4; ++j)
          r[ti[j]] = fmaf(mi[i] * mi[j], Dqk[i][j], fmaf(mi[j], Fk[j], base));
        r[3] = fmaf(mi[i] * m3, Dqv[i], fmaf(m3, F3, base));
        sm_accum(r, w5);
      }
      const float base = fmaf(m3, E3, Gh);
#pragma unroll
      for (int j = 0; j < 4; ++j)
        r[ti[j]] = fmaf(m3 * mi[j], Dvk[j], fmaf(mi[j], Fk[j], base));
      r[3] = fmaf(m3 * m3, D33, fmaf(m3, F3, base));
      sm_accum(r, w5);
    }

    // meanO = bias-row (sumw == 1 exactly: each softmax row contributes 0.2)
    //         + 6 weighted rows of PvB (bf16), fp32 accumulate
    const float w3m = w5[3] * m3;
    const int   vr[6] = {R[0], R[1], R[2], R[3], 140, 141};
    const float vc[6] = {w5[0] * m[0], w5[1] * m[1], w5[2] * m[2], w5[4] * m[4],
                         w3m * val, w3m};
#pragma unroll
    for (int dc = 0; dc < 4; ++dc) {
      float acc[8];
      {
        uint4 pk = *(const uint4*)(PvB + 142 * 128 + dc * 32 + h * 8);
        unpack8(acc, pk);
      }
#pragma unroll
      for (int p = 0; p < 6; ++p) {
        uint4 pk = *(const uint4*)(PvB + (size_t)vr[p] * 128 + dc * 32 + h * 8);
        float v[8];
        unpack8(v, pk);
#pragma unroll
        for (int j = 0; j < 8; ++j) acc[j] = fmaf(vc[p], v[j], acc[j]);
      }
      uint4 pk;
      pk.x = (unsigned)f32_bf16(acc[0]) | ((unsigned)f32_bf16(acc[1]) << 16);
      pk.y = (unsigned)f32_bf16(acc[2]) | ((unsigned)f32_bf16(acc[3]) << 16);
      pk.z = (unsigned)f32_bf16(acc[4]) | ((unsigned)f32_bf16(acc[5]) << 16);
      pk.w = (unsigned)f32_bf16(acc[6]) | ((unsigned)f32_bf16(acc[7]) << 16);
      *(uint4*)((char*)sMean + (size_t)lr * (LDS_STRIDE * 2) + h * 64 + dc * 16) = pk;
    }
  }
  __syncthreads();

  // ---- Phase B: out[64][768] = meanO @ W2^T + b2, MFMA 16x16x32 bf16 ----
  // mh-outer (2 halves of 32 rows): afrag live = 32 VGPRs, W2 re-read only 2x
  // per block from L2. Stores are nontemporal (write-once stream, skip L2).
  {
    const int w    = tid >> 6;   // wave 0..3 -> cols [w*192, +192)
    const int lane = tid & 63;
    const int ln16 = lane & 15;
    const int lq   = lane >> 4;
    const int rowbase = blockIdx.x * 64;

#pragma unroll
    for (int mh = 0; mh < 2; ++mh) {
      bf16x8 afrag[2][4];
#pragma unroll
      for (int mt = 0; mt < 2; ++mt)
#pragma unroll
        for (int ks = 0; ks < 4; ++ks)
          afrag[mt][ks] = *(const bf16x8*)((const char*)sMean +
                            (size_t)(mh * 32 + mt * 16 + ln16) * (LDS_STRIDE * 2) +
                            ks * 64 + lq * 16);
      const int r0 = rowbase + mh * 32 + lq * 4;   // D: row=(lane>>4)*4+reg, col=lane&15

#pragma unroll 2
      for (int nt = 0; nt < 12; ++nt) {
        const int col = w * 192 + nt * 16 + ln16;
        const unsigned short* bp = W2 + (size_t)col * 128 + lq * 8;
        bf16x8 bfrag[4];
#pragma unroll
        for (int ks = 0; ks < 4; ++ks)
          bfrag[ks] = *(const bf16x8*)(bp + ks * 32);

        floatx4 acc[2];
        acc[0] = (floatx4){0.f, 0.f, 0.f, 0.f};
        acc[1] = (floatx4){0.f, 0.f, 0.f, 0.f};
#pragma unroll
        for (int ks = 0; ks < 4; ++ks) {
          acc[0] = __builtin_amdgcn_mfma_f32_16x16x32_bf16(afrag[0][ks], bfrag[ks], acc[0], 0, 0, 0);
          acc[1] = __builtin_amdgcn_mfma_f32_16x16x32_bf16(afrag[1][ks], bfrag[ks], acc[1], 0, 0, 0);
        }

        const float bb = b2[col];
#pragma unroll
        for (int mt = 0; mt < 2; ++mt)
#pragma unroll
          for (int r = 0; r < 4; ++r)
            __builtin_nontemporal_store(acc[mt][r] + bb,
                &out[(size_t)(r0 + mt * 16 + r) * 768 + col]);
      }
    }
  }
}

extern "C" void kernel_launch(void* const* d_in, const int* in_sizes, int n_in,
                              void* d_out, int out_size, void* d_ws, size_t ws_size,
                              hipStream_t stream) {
  const int*   dev_ids = (const int*)d_in[0];
  const int*   pse_ids = (const int*)d_in[1];
  const int*   att_ids = (const int*)d_in[2];
  const int*   unt_ids = (const int*)d_in[3];
  const float* values  = (const float*)d_in[4];
  const int*   mask    = (const int*)d_in[5];
  const float* dev_t   = (const float*)d_in[6];
  const float* pse_t   = (const float*)d_in[7];
  const float* att_t   = (const float*)d_in[8];
  const float* unt_t   = (const float*)d_in[9];
  const float* val_w   = (const float*)d_in[10];
  const float* val_b   = (const float*)d_in[11];
  const float* ipw     = (const float*)d_in[12];
  const float* ipb     = (const float*)d_in[13];
  const float* opw     = (const float*)d_in[14];
  const float* opb     = (const float*)d_in[15];
  const float* out_w   = (const float*)d_in[16];
  const float* out_b   = (const float*)d_in[17];
  float* out = (float*)d_out;

  const int N = in_sizes[0];

  // workspace layout (float units):
  // proj 54528 | b2 768 | W2(bf16) 24576 | D 80656 | E 568 | F 568 | G 4 | PvB(bf16) 9152
  float* proj = (float*)d_ws;
  float* b2   = proj + 54528;
  unsigned short* W2 = (unsigned short*)(b2 + 768);
  float* D = (float*)(W2 + 768 * 128);
  float* E = D + 142 * 142 * 4;
  float* F = E + 142 * 4;
  float* G = F + 142 * 4;
  unsigned short* PvB = (unsigned short*)(G + 4);   // byte offset 646672, 16B aligned

  k_proj_tables<<<142, 384, 0, stream>>>(dev_t, pse_t, att_t, unt_t, val_w, val_b, ipw, proj);
  k_fuse_w2<<<768, 128, 0, stream>>>(out_w, opw, opb, out_b, W2, b2);
  k_dots<<<142, 256, 0, stream>>>(proj, ipb, D, E, F, G, PvB);
  k_main<<<N / 64, 256, 0, stream>>>(dev_ids, pse_ids, att_ids, unt_ids, values, mask,
                                     D, E, F, G, PvB, W2, b2, out);
  (void)out_size; (void)ws_size; (void)n_in;
}

// Round 9
// 527.236 us; speedup vs baseline: 1.0078x; 1.0078x over previous
//
#include <hip/hip_runtime.h>

// CompositionalEmbedding on MI355X — round 11 (re-submission of round 7; fourth
// attempt — three consecutive acquisition timeouts).
// Round-6 verdict (only measurement this session): passed, absmax 3.9e-3, 531 µs
// ≈ 254 µs harness fill + ~25 µs P1-P3 + ~250 µs k_main (just under top-5 cutoff).
// Prior session ≈ 254 + 25 + ~210 with plain stores at (256,2).
// Suspect #1 for the +35-40 µs: nt stores forfeit cross-iteration 64B->128B
// line merging in L2 (each quarter-wave writes a 64-B segment; the adjacent
// half-line comes from the NEXT nt iteration — plain stores merge in L2, nt
// writes partial lines straight through). Matches the ~17% write-BW loss.
// Suspect #2 (less likely, ~110 VGPR by 3x-audited hand count): spills at (256,4).
// SINGLE change vs round 6: nt stores -> plain stores. Keep (256,4), mh-outer
// Phase B, and all Phase-A algebra (verified passing at round 6).

typedef __attribute__((ext_vector_type(8))) short bf16x8;
typedef __attribute__((ext_vector_type(4))) float floatx4;

__device__ __forceinline__ unsigned short f32_bf16(float f) {
  unsigned int x = __float_as_uint(f);
  x += 0x7FFFu + ((x >> 16) & 1u);   // RNE
  return (unsigned short)(x >> 16);
}

// ---------------- P1: proj[142][384] = {table rows, val_w, val_b} @ in_proj_w^T
__global__ void k_proj_tables(const float* __restrict__ dev_t, const float* __restrict__ pse_t,
                              const float* __restrict__ att_t, const float* __restrict__ unt_t,
                              const float* __restrict__ val_w, const float* __restrict__ val_b,
                              const float* __restrict__ W /*[384][128]*/,
                              float* __restrict__ out /*[142][384]*/) {
  __shared__ float src[128];
  int r = blockIdx.x;
  const float* s;
  if (r < 10)        s = dev_t + r * 128;
  else if (r < 20)   s = pse_t + (r - 10) * 128;
  else if (r < 120)  s = att_t + (r - 20) * 128;
  else if (r < 140)  s = unt_t + (r - 120) * 128;
  else if (r == 140) s = val_w;           // [128][1] contiguous
  else               s = val_b;
  int t = threadIdx.x;                    // 384 threads
  if (t < 128) src[t] = s[t];
  __syncthreads();
  const float* wr = W + t * 128;
  float acc = 0.f;
#pragma unroll 8
  for (int e = 0; e < 128; ++e) acc = fmaf(wr[e], src[e], acc);
  out[r * 384 + t] = acc;
}

// ---------------- P2: W2[768][128] bf16 = out_w @ out_proj_w ; b2 = out_w@out_proj_b + out_b
__global__ void k_fuse_w2(const float* __restrict__ out_w /*[768][128]*/,
                          const float* __restrict__ opw /*[128][128]*/,
                          const float* __restrict__ opb /*[128]*/,
                          const float* __restrict__ out_b /*[768]*/,
                          unsigned short* __restrict__ W2 /*[768][128] bf16*/,
                          float* __restrict__ b2 /*[768]*/) {
  __shared__ float row[128];
  __shared__ float red[128];
  int r = blockIdx.x, c = threadIdx.x;    // 128 threads
  row[c] = out_w[r * 128 + c];
  __syncthreads();
  float acc = 0.f;
#pragma unroll 8
  for (int k = 0; k < 128; ++k) acc = fmaf(row[k], opw[k * 128 + c], acc);
  W2[r * 128 + c] = f32_bf16(acc);
  red[c] = row[c] * opb[c];
  __syncthreads();
#pragma unroll
  for (int s = 64; s > 0; s >>= 1) {
    if (c < s) red[c] += red[c + s];
    __syncthreads();
  }
  if (c == 0) b2[r] = red[0] + out_b[r];
}

// ---------------- P3: score dot tables (PRE-SCALED by 1/sqrt(32)) + bf16 V table
// D[q][k][h] = SC * (q-slice proj[q], head h) . (k-slice proj[k], head h)
// E[q][h] = SC * Pq_q . bk ; F[k][h] = SC * bq . Pk_k ; G[h] = SC * bq . bk
// PvB[row][dc][h][8] bf16; row 142 = v-slice of bias (NOT scaled — it's V data).
__global__ void k_dots(const float* __restrict__ proj, const float* __restrict__ bias,
                       float* __restrict__ D, float* __restrict__ E,
                       float* __restrict__ F, float* __restrict__ G,
                       unsigned short* __restrict__ PvB) {
  const float SC = 0.17677669529663687f;  // 1/sqrt(32)
  __shared__ float qs[128];
  const int q = blockIdx.x;     // 0..141
  const int t = threadIdx.x;    // 256
  if (t < 128) qs[t] = proj[q * 384 + t];
  __syncthreads();
  for (int o = t; o < 568; o += 256) {
    const int k = o >> 2, h = o & 3;
    const float* kp = proj + k * 384 + 128 + h * 32;
    const float* qp = qs + h * 32;
    float acc = 0.f;
#pragma unroll
    for (int d = 0; d < 32; ++d) acc = fmaf(qp[d], kp[d], acc);
    D[(size_t)(q * 142 + k) * 4 + h] = acc * SC;
  }
  if (t < 4) {
    const int h = t;
    float e = 0.f, f = 0.f;
#pragma unroll
    for (int d = 0; d < 32; ++d) {
      e = fmaf(qs[h * 32 + d], bias[128 + h * 32 + d], e);
      f = fmaf(bias[h * 32 + d], proj[q * 384 + 128 + h * 32 + d], f);
    }
    E[q * 4 + h] = e * SC;
    F[q * 4 + h] = f * SC;
    if (q == 0) {
      float g = 0.f;
#pragma unroll
      for (int d = 0; d < 32; ++d) g = fmaf(bias[h * 32 + d], bias[128 + h * 32 + d], g);
      G[h] = g * SC;
    }
  }
  if (t >= 128) {
    const int x = t - 128;                       // 0..127, col in v-slice
    const int h = x >> 5, dc = (x >> 3) & 3, j = x & 7;
    PvB[q * 128 + dc * 32 + h * 8 + j] = f32_bf16(proj[q * 384 + 256 + x]);
    if (q == 0) PvB[142 * 128 + dc * 32 + h * 8 + j] = f32_bf16(bias[256 + x]);
  }
}

// ---------------- main: 64 rows/block, 256 threads
#define LDS_STRIDE 136   // bf16 elems/row: 272 B; row-stride 4 banks -> conflict-neutral b128

__device__ __forceinline__ void unpack8(float d[8], uint4 p) {
  d[0] = __uint_as_float(p.x << 16); d[1] = __uint_as_float(p.x & 0xffff0000u);
  d[2] = __uint_as_float(p.y << 16); d[3] = __uint_as_float(p.y & 0xffff0000u);
  d[4] = __uint_as_float(p.z << 16); d[5] = __uint_as_float(p.z & 0xffff0000u);
  d[6] = __uint_as_float(p.w << 16); d[7] = __uint_as_float(p.w & 0xffff0000u);
}

__device__ __forceinline__ void sm_accum(const float r[5], float w5[5]) {
  // scores pre-scaled; |s| << 88 so exp without max-shift is safe
  float e0 = __expf(r[0]), e1 = __expf(r[1]), e2 = __expf(r[2]),
        e3 = __expf(r[3]), e4 = __expf(r[4]);
  const float inv = 0.2f / (e0 + e1 + e2 + e3 + e4);   // mean over q folded in
  w5[0] = fmaf(e0, inv, w5[0]); w5[1] = fmaf(e1, inv, w5[1]);
  w5[2] = fmaf(e2, inv, w5[2]); w5[3] = fmaf(e3, inv, w5[3]);
  w5[4] = fmaf(e4, inv, w5[4]);
}

__global__ __launch_bounds__(256, 4)   // 4 blocks/CU (<=128 VGPR; ~110 by hand count)
void k_main(const int* __restrict__ dev_ids, const int* __restrict__ pse_ids,
            const int* __restrict__ att_ids, const int* __restrict__ unt_ids,
            const float* __restrict__ values, const int* __restrict__ mask,
            const float* __restrict__ D, const float* __restrict__ E,
            const float* __restrict__ F, const float* __restrict__ G,
            const unsigned short* __restrict__ PvB,
            const unsigned short* __restrict__ W2 /*[768][128] bf16*/,
            const float* __restrict__ b2 /*[768]*/,
            float* __restrict__ out /*[N][768]*/) {
  __shared__ __align__(16) unsigned short sMean[64 * LDS_STRIDE];

  const int tid = threadIdx.x;
  const int lr = tid >> 2;        // local row 0..63
  const int h  = tid & 3;         // head 0..3 (adjacent lanes = 4 heads -> 16B coalesced gathers)
  const int n  = blockIdx.x * 64 + lr;

  // ---- Phase A: scores from precomputed (pre-scaled) dots, weighted V combine ----
  {
    int R[4];
    R[0] = dev_ids[n];
    R[1] = 10 + pse_ids[n];
    R[2] = 20 + att_ids[n];
    R[3] = 120 + unt_ids[n];
    const float val = values[n];
    float m[5];
#pragma unroll
    for (int t = 0; t < 5; ++t) m[t] = (float)mask[n * 5 + t];
    const float mi[4] = {m[0], m[1], m[2], m[4]};
    const float m3 = m[3];

    // gathers; fold val into the (w,b) pairs immediately to cut live regs
    float Dqk[4][4], Dqv[4], Dvk[4], Eq[4], Fk[4];
#pragma unroll
    for (int i = 0; i < 4; ++i) {
      const size_t ri = (size_t)R[i] * 568 + h;   // (q*142+k)*4+h with k folded below
#pragma unroll
      for (int j = 0; j < 4; ++j)
        Dqk[i][j] = D[ri + R[j] * 4];
      Dqv[i] = fmaf(val, D[ri + 560], D[ri + 564]);                 // k=140,141
      Dvk[i] = fmaf(val, D[(size_t)79520 + R[i] * 4 + h],           // q=140
                         D[(size_t)80088 + R[i] * 4 + h]);          // q=141
      Eq[i]  = E[R[i] * 4 + h];
      Fk[i]  = F[R[i] * 4 + h];
    }
    const float E3  = fmaf(val, E[560 + h], E[564 + h]);
    const float F3  = fmaf(val, F[560 + h], F[564 + h]);
    const float D33 = fmaf(val * val, D[80080 + h],
                      fmaf(val, D[80084 + h] + D[80648 + h], D[80652 + h]));
    const float Gh  = G[h];

    // row-streamed softmax: one 5-score row live at a time
    const int ti[4] = {0, 1, 2, 4};
    float w5[5] = {0.f, 0.f, 0.f, 0.f, 0.f};
    {
      float r[5];
#pragma unroll
      for (int i = 0; i < 4; ++i) {
        const float base = fmaf(mi[i], Eq[i], Gh);
#pragma unroll
        for (int j = 0; j < 4; ++j)
          r[ti[j]] = fmaf(mi[i] * mi[j], Dqk[i][j], fmaf(mi[j], Fk[j], base));
        r[3] = fmaf(mi[i] * m3, Dqv[i], fmaf(m3, F3, base));
        sm_accum(r, w5);
      }
      const float base = fmaf(m3, E3, Gh);
#pragma unroll
      for (int j = 0; j < 4; ++j)
        r[ti[j]] = fmaf(m3 * mi[j], Dvk[j], fmaf(mi[j], Fk[j], base));
      r[3] = fmaf(m3 * m3, D33, fmaf(m3, F3, base));
      sm_accum(r, w5);
    }

    // meanO = bias-row (sumw == 1 exactly: each softmax row contributes 0.2)
    //         + 6 weighted rows of PvB (bf16), fp32 accumulate
    const float w3m = w5[3] * m3;
    const int   vr[6] = {R[0], R[1], R[2], R[3], 140, 141};
    const float vc[6] = {w5[0] * m[0], w5[1] * m[1], w5[2] * m[2], w5[4] * m[4],
                         w3m * val, w3m};
#pragma unroll
    for (int dc = 0; dc < 4; ++dc) {
      float acc[8];
      {
        uint4 pk = *(const uint4*)(PvB + 142 * 128 + dc * 32 + h * 8);
        unpack8(acc, pk);
      }
#pragma unroll
      for (int p = 0; p < 6; ++p) {
        uint4 pk = *(const uint4*)(PvB + (size_t)vr[p] * 128 + dc * 32 + h * 8);
        float v[8];
        unpack8(v, pk);
#pragma unroll
        for (int j = 0; j < 8; ++j) acc[j] = fmaf(vc[p], v[j], acc[j]);
      }
      uint4 pk;
      pk.x = (unsigned)f32_bf16(acc[0]) | ((unsigned)f32_bf16(acc[1]) << 16);
      pk.y = (unsigned)f32_bf16(acc[2]) | ((unsigned)f32_bf16(acc[3]) << 16);
      pk.z = (unsigned)f32_bf16(acc[4]) | ((unsigned)f32_bf16(acc[5]) << 16);
      pk.w = (unsigned)f32_bf16(acc[6]) | ((unsigned)f32_bf16(acc[7]) << 16);
      *(uint4*)((char*)sMean + (size_t)lr * (LDS_STRIDE * 2) + h * 64 + dc * 16) = pk;
    }
  }
  __syncthreads();

  // ---- Phase B: out[64][768] = meanO @ W2^T + b2, MFMA 16x16x32 bf16 ----
  // mh-outer (2 halves of 32 rows): afrag live = 32 VGPRs, W2 re-read only 2x
  // per block from L2. PLAIN stores: each quarter-wave writes a 64-B segment;
  // the adjacent half-line comes from the next nt iteration — L2 merges them
  // into full-line writebacks. nt stores forfeited that merge (round-6 +35 µs).
  {
    const int w    = tid >> 6;   // wave 0..3 -> cols [w*192, +192)
    const int lane = tid & 63;
    const int ln16 = lane & 15;
    const int lq   = lane >> 4;
    const int rowbase = blockIdx.x * 64;

#pragma unroll
    for (int mh = 0; mh < 2; ++mh) {
      bf16x8 afrag[2][4];
#pragma unroll
      for (int mt = 0; mt < 2; ++mt)
#pragma unroll
        for (int ks = 0; ks < 4; ++ks)
          afrag[mt][ks] = *(const bf16x8*)((const char*)sMean +
                            (size_t)(mh * 32 + mt * 16 + ln16) * (LDS_STRIDE * 2) +
                            ks * 64 + lq * 16);
      const int r0 = rowbase + mh * 32 + lq * 4;   // D: row=(lane>>4)*4+reg, col=lane&15

#pragma unroll 2
      for (int nt = 0; nt < 12; ++nt) {
        const int col = w * 192 + nt * 16 + ln16;
        const unsigned short* bp = W2 + (size_t)col * 128 + lq * 8;
        bf16x8 bfrag[4];
#pragma unroll
        for (int ks = 0; ks < 4; ++ks)
          bfrag[ks] = *(const bf16x8*)(bp + ks * 32);

        floatx4 acc[2];
        acc[0] = (floatx4){0.f, 0.f, 0.f, 0.f};
        acc[1] = (floatx4){0.f, 0.f, 0.f, 0.f};
#pragma unroll
        for (int ks = 0; ks < 4; ++ks) {
          acc[0] = __builtin_amdgcn_mfma_f32_16x16x32_bf16(afrag[0][ks], bfrag[ks], acc[0], 0, 0, 0);
          acc[1] = __builtin_amdgcn_mfma_f32_16x16x32_bf16(afrag[1][ks], bfrag[ks], acc[1], 0, 0, 0);
        }

        const float bb = b2[col];
#pragma unroll
        for (int mt = 0; mt < 2; ++mt)
#pragma unroll
          for (int r = 0; r < 4; ++r)
            out[(size_t)(r0 + mt * 16 + r) * 768 + col] = acc[mt][r] + bb;
      }
    }
  }
}

extern "C" void kernel_launch(void* const* d_in, const int* in_sizes, int n_in,
                              void* d_out, int out_size, void* d_ws, size_t ws_size,
                              hipStream_t stream) {
  const int*   dev_ids = (const int*)d_in[0];
  const int*   pse_ids = (const int*)d_in[1];
  const int*   att_ids = (const int*)d_in[2];
  const int*   unt_ids = (const int*)d_in[3];
  const float* values  = (const float*)d_in[4];
  const int*   mask    = (const int*)d_in[5];
  const float* dev_t   = (const float*)d_in[6];
  const float* pse_t   = (const float*)d_in[7];
  const float* att_t   = (const float*)d_in[8];
  const float* unt_t   = (const float*)d_in[9];
  const float* val_w   = (const float*)d_in[10];
  const float* val_b   = (const float*)d_in[11];
  const float* ipw     = (const float*)d_in[12];
  const float* ipb     = (const float*)d_in[13];
  const float* opw     = (const float*)d_in[14];
  const float* opb     = (const float*)d_in[15];
  const float* out_w   = (const float*)d_in[16];
  const float* out_b   = (const float*)d_in[17];
  float* out = (float*)d_out;

  const int N = in_sizes[0];

  // workspace layout (float units):
  // proj 54528 | b2 768 | W2(bf16) 24576 | D 80656 | E 568 | F 568 | G 4 | PvB(bf16) 9152
  float* proj = (float*)d_ws;
  float* b2   = proj + 54528;
  unsigned short* W2 = (unsigned short*)(b2 + 768);
  float* D = (float*)(W2 + 768 * 128);
  float* E = D + 142 * 142 * 4;
  float* F = E + 142 * 4;
  float* G = F + 142 * 4;
  unsigned short* PvB = (unsigned short*)(G + 4);   // byte offset 646672, 16B aligned

  k_proj_tables<<<142, 384, 0, stream>>>(dev_t, pse_t, att_t, unt_t, val_w, val_b, ipw, proj);
  k_fuse_w2<<<768, 128, 0, stream>>>(out_w, opw, opb, out_b, W2, b2);
  k_dots<<<142, 256, 0, stream>>>(proj, ipb, D, E, F, G, PvB);
  k_main<<<N / 64, 256, 0, stream>>>(dev_ids, pse_ids, att_ids, unt_ids, values, mask,
                                     D, E, F, G, PvB, W2, b2, out);
  (void)out_size; (void)ws_size; (void)n_in;
}

// Round 16
// 490.276 us; speedup vs baseline: 1.0838x; 1.0754x over previous
//
#include <hip/hip_runtime.h>

// CompositionalEmbedding on MI355X — round 18 (re-submission of round 12; sixth
// consecutive acquisition timeout on this exact source).
// Measured history: r6 = 531 µs (nt, (256,4), mh-outer); r9 = 527 µs (plain,
// same) -> nt innocent. Prior session: 490 µs (plain, (256,2), single-pass B).
// Remaining suspects for the ~+35 µs vs baseline: mh-outer Phase B (+402 MB L2
// reads) and/or (256,4) regalloc pressure. This kernel removes both:
//   - Phase B: single-pass afrag[4][4], W2 read ONCE per block (== prior
//     session's verified structure); unroll-2 peak ~138 VGPR < 170 cap
//   - __launch_bounds__(256, 3): +50% occupancy vs baseline (256,2); LDS
//     52 KB/CU at 3 blocks -> VGPR-capped as intended, no spill
//   - plain stores (r9-validated), Phase-A algebra (r6+r9-validated)

typedef __attribute__((ext_vector_type(8))) short bf16x8;
typedef __attribute__((ext_vector_type(4))) float floatx4;

__device__ __forceinline__ unsigned short f32_bf16(float f) {
  unsigned int x = __float_as_uint(f);
  x += 0x7FFFu + ((x >> 16) & 1u);   // RNE
  return (unsigned short)(x >> 16);
}

// ---------------- P1: proj[142][384] = {table rows, val_w, val_b} @ in_proj_w^T
__global__ void k_proj_tables(const float* __restrict__ dev_t, const float* __restrict__ pse_t,
                              const float* __restrict__ att_t, const float* __restrict__ unt_t,
                              const float* __restrict__ val_w, const float* __restrict__ val_b,
                              const float* __restrict__ W /*[384][128]*/,
                              float* __restrict__ out /*[142][384]*/) {
  __shared__ float src[128];
  int r = blockIdx.x;
  const float* s;
  if (r < 10)        s = dev_t + r * 128;
  else if (r < 20)   s = pse_t + (r - 10) * 128;
  else if (r < 120)  s = att_t + (r - 20) * 128;
  else if (r < 140)  s = unt_t + (r - 120) * 128;
  else if (r == 140) s = val_w;           // [128][1] contiguous
  else               s = val_b;
  int t = threadIdx.x;                    // 384 threads
  if (t < 128) src[t] = s[t];
  __syncthreads();
  const float* wr = W + t * 128;
  float acc = 0.f;
#pragma unroll 8
  for (int e = 0; e < 128; ++e) acc = fmaf(wr[e], src[e], acc);
  out[r * 384 + t] = acc;
}

// ---------------- P2: W2[768][128] bf16 = out_w @ out_proj_w ; b2 = out_w@out_proj_b + out_b
__global__ void k_fuse_w2(const float* __restrict__ out_w /*[768][128]*/,
                          const float* __restrict__ opw /*[128][128]*/,
                          const float* __restrict__ opb /*[128]*/,
                          const float* __restrict__ out_b /*[768]*/,
                          unsigned short* __restrict__ W2 /*[768][128] bf16*/,
                          float* __restrict__ b2 /*[768]*/) {
  __shared__ float row[128];
  __shared__ float red[128];
  int r = blockIdx.x, c = threadIdx.x;    // 128 threads
  row[c] = out_w[r * 128 + c];
  __syncthreads();
  float acc = 0.f;
#pragma unroll 8
  for (int k = 0; k < 128; ++k) acc = fmaf(row[k], opw[k * 128 + c], acc);
  W2[r * 128 + c] = f32_bf16(acc);
  red[c] = row[c] * opb[c];
  __syncthreads();
#pragma unroll
  for (int s = 64; s > 0; s >>= 1) {
    if (c < s) red[c] += red[c + s];
    __syncthreads();
  }
  if (c == 0) b2[r] = red[0] + out_b[r];
}

// ---------------- P3: score dot tables (PRE-SCALED by 1/sqrt(32)) + bf16 V table
// D[q][k][h] = SC * (q-slice proj[q], head h) . (k-slice proj[k], head h)
// E[q][h] = SC * Pq_q . bk ; F[k][h] = SC * bq . Pk_k ; G[h] = SC * bq . bk
// PvB[row][dc][h][8] bf16; row 142 = v-slice of bias (NOT scaled — it's V data).
__global__ void k_dots(const float* __restrict__ proj, const float* __restrict__ bias,
                       float* __restrict__ D, float* __restrict__ E,
                       float* __restrict__ F, float* __restrict__ G,
                       unsigned short* __restrict__ PvB) {
  const float SC = 0.17677669529663687f;  // 1/sqrt(32)
  __shared__ float qs[128];
  const int q = blockIdx.x;     // 0..141
  const int t = threadIdx.x;    // 256
  if (t < 128) qs[t] = proj[q * 384 + t];
  __syncthreads();
  for (int o = t; o < 568; o += 256) {
    const int k = o >> 2, h = o & 3;
    const float* kp = proj + k * 384 + 128 + h * 32;
    const float* qp = qs + h * 32;
    float acc = 0.f;
#pragma unroll
    for (int d = 0; d < 32; ++d) acc = fmaf(qp[d], kp[d], acc);
    D[(size_t)(q * 142 + k) * 4 + h] = acc * SC;
  }
  if (t < 4) {
    const int h = t;
    float e = 0.f, f = 0.f;
#pragma unroll
    for (int d = 0; d < 32; ++d) {
      e = fmaf(qs[h * 32 + d], bias[128 + h * 32 + d], e);
      f = fmaf(bias[h * 32 + d], proj[q * 384 + 128 + h * 32 + d], f);
    }
    E[q * 4 + h] = e * SC;
    F[q * 4 + h] = f * SC;
    if (q == 0) {
      float g = 0.f;
#pragma unroll
      for (int d = 0; d < 32; ++d) g = fmaf(bias[h * 32 + d], bias[128 + h * 32 + d], g);
      G[h] = g * SC;
    }
  }
  if (t >= 128) {
    const int x = t - 128;                       // 0..127, col in v-slice
    const int h = x >> 5, dc = (x >> 3) & 3, j = x & 7;
    PvB[q * 128 + dc * 32 + h * 8 + j] = f32_bf16(proj[q * 384 + 256 + x]);
    if (q == 0) PvB[142 * 128 + dc * 32 + h * 8 + j] = f32_bf16(bias[256 + x]);
  }
}

// ---------------- main: 64 rows/block, 256 threads
#define LDS_STRIDE 136   // bf16 elems/row: 272 B; row-stride 4 banks -> conflict-neutral b128

__device__ __forceinline__ void unpack8(float d[8], uint4 p) {
  d[0] = __uint_as_float(p.x << 16); d[1] = __uint_as_float(p.x & 0xffff0000u);
  d[2] = __uint_as_float(p.y << 16); d[3] = __uint_as_float(p.y & 0xffff0000u);
  d[4] = __uint_as_float(p.z << 16); d[5] = __uint_as_float(p.z & 0xffff0000u);
  d[6] = __uint_as_float(p.w << 16); d[7] = __uint_as_float(p.w & 0xffff0000u);
}

__device__ __forceinline__ void sm_accum(const float r[5], float w5[5]) {
  // scores pre-scaled; |s| << 88 so exp without max-shift is safe
  float e0 = __expf(r[0]), e1 = __expf(r[1]), e2 = __expf(r[2]),
        e3 = __expf(r[3]), e4 = __expf(r[4]);
  const float inv = 0.2f / (e0 + e1 + e2 + e3 + e4);   // mean over q folded in
  w5[0] = fmaf(e0, inv, w5[0]); w5[1] = fmaf(e1, inv, w5[1]);
  w5[2] = fmaf(e2, inv, w5[2]); w5[3] = fmaf(e3, inv, w5[3]);
  w5[4] = fmaf(e4, inv, w5[4]);
}

__global__ __launch_bounds__(256, 3)   // 3 blocks/CU: VGPR cap 170 >> ~138 worst-case peak
void k_main(const int* __restrict__ dev_ids, const int* __restrict__ pse_ids,
            const int* __restrict__ att_ids, const int* __restrict__ unt_ids,
            const float* __restrict__ values, const int* __restrict__ mask,
            const float* __restrict__ D, const float* __restrict__ E,
            const float* __restrict__ F, const float* __restrict__ G,
            const unsigned short* __restrict__ PvB,
            const unsigned short* __restrict__ W2 /*[768][128] bf16*/,
            const float* __restrict__ b2 /*[768]*/,
            float* __restrict__ out /*[N][768]*/) {
  __shared__ __align__(16) unsigned short sMean[64 * LDS_STRIDE];

  const int tid = threadIdx.x;
  const int lr = tid >> 2;        // local row 0..63
  const int h  = tid & 3;         // head 0..3 (adjacent lanes = 4 heads -> 16B coalesced gathers)
  const int n  = blockIdx.x * 64 + lr;

  // ---- Phase A: scores from precomputed (pre-scaled) dots, weighted V combine ----
  {
    int R[4];
    R[0] = dev_ids[n];
    R[1] = 10 + pse_ids[n];
    R[2] = 20 + att_ids[n];
    R[3] = 120 + unt_ids[n];
    const float val = values[n];
    float m[5];
#pragma unroll
    for (int t = 0; t < 5; ++t) m[t] = (float)mask[n * 5 + t];
    const float mi[4] = {m[0], m[1], m[2], m[4]};
    const float m3 = m[3];

    // gathers; fold val into the (w,b) pairs immediately to cut live regs
    float Dqk[4][4], Dqv[4], Dvk[4], Eq[4], Fk[4];
#pragma unroll
    for (int i = 0; i < 4; ++i) {
      const size_t ri = (size_t)R[i] * 568 + h;   // (q*142+k)*4+h with k folded below
#pragma unroll
      for (int j = 0; j < 4; ++j)
        Dqk[i][j] = D[ri + R[j] * 4];
      Dqv[i] = fmaf(val, D[ri + 560], D[ri + 564]);                 // k=140,141
      Dvk[i] = fmaf(val, D[(size_t)79520 + R[i] * 4 + h],           // q=140
                         D[(size_t)80088 + R[i] * 4 + h]);          // q=141
      Eq[i]  = E[R[i] * 4 + h];
      Fk[i]  = F[R[i] * 4 + h];
    }
    const float E3  = fmaf(val, E[560 + h], E[564 + h]);
    const float F3  = fmaf(val, F[560 + h], F[564 + h]);
    const float D33 = fmaf(val * val, D[80080 + h],
                      fmaf(val, D[80084 + h] + D[80648 + h], D[80652 + h]));
    const float Gh  = G[h];

    // row-streamed softmax: one 5-score row live at a time
    const int ti[4] = {0, 1, 2, 4};
    float w5[5] = {0.f, 0.f, 0.f, 0.f, 0.f};
    {
      float r[5];
#pragma unroll
      for (int i = 0; i < 4; ++i) {
        const float base = fmaf(mi[i], Eq[i], Gh);
#pragma unroll
        for (int j = 0; j < 4; ++j)
          r[ti[j]] = fmaf(mi[i] * mi[j], Dqk[i][j], fmaf(mi[j], Fk[j], base));
        r[3] = fmaf(mi[i] * m3, Dqv[i], fmaf(m3, F3, base));
        sm_accum(r, w5);
      }
      const float base = fmaf(m3, E3, Gh);
#pragma unroll
      for (int j = 0; j < 4; ++j)
        r[ti[j]] = fmaf(m3 * mi[j], Dvk[j], fmaf(mi[j], Fk[j], base));
      r[3] = fmaf(m3 * m3, D33, fmaf(m3, F3, base));
      sm_accum(r, w5);
    }

    // meanO = bias-row (sumw == 1 exactly: each softmax row contributes 0.2)
    //         + 6 weighted rows of PvB (bf16), fp32 accumulate
    const float w3m = w5[3] * m3;
    const int   vr[6] = {R[0], R[1], R[2], R[3], 140, 141};
    const float vc[6] = {w5[0] * m[0], w5[1] * m[1], w5[2] * m[2], w5[4] * m[4],
                         w3m * val, w3m};
#pragma unroll
    for (int dc = 0; dc < 4; ++dc) {
      float acc[8];
      {
        uint4 pk = *(const uint4*)(PvB + 142 * 128 + dc * 32 + h * 8);
        unpack8(acc, pk);
      }
#pragma unroll
      for (int p = 0; p < 6; ++p) {
        uint4 pk = *(const uint4*)(PvB + (size_t)vr[p] * 128 + dc * 32 + h * 8);
        float v[8];
        unpack8(v, pk);
#pragma unroll
        for (int j = 0; j < 8; ++j) acc[j] = fmaf(vc[p], v[j], acc[j]);
      }
      uint4 pk;
      pk.x = (unsigned)f32_bf16(acc[0]) | ((unsigned)f32_bf16(acc[1]) << 16);
      pk.y = (unsigned)f32_bf16(acc[2]) | ((unsigned)f32_bf16(acc[3]) << 16);
      pk.z = (unsigned)f32_bf16(acc[4]) | ((unsigned)f32_bf16(acc[5]) << 16);
      pk.w = (unsigned)f32_bf16(acc[6]) | ((unsigned)f32_bf16(acc[7]) << 16);
      *(uint4*)((char*)sMean + (size_t)lr * (LDS_STRIDE * 2) + h * 64 + dc * 16) = pk;
    }
  }
  __syncthreads();

  // ---- Phase B: out[64][768] = meanO @ W2^T + b2, MFMA 16x16x32 bf16 ----
  // Single-pass (prior session's verified structure): afrag[4][4] held (64
  // VGPRs), W2 read ONCE per block — no mh-outer re-read traffic. Plain stores.
  {
    const int w    = tid >> 6;   // wave 0..3 -> cols [w*192, +192)
    const int lane = tid & 63;
    const int ln16 = lane & 15;
    const int lq   = lane >> 4;

    bf16x8 afrag[4][4];
#pragma unroll
    for (int mt = 0; mt < 4; ++mt)
#pragma unroll
      for (int ks = 0; ks < 4; ++ks)
        afrag[mt][ks] = *(const bf16x8*)((const char*)sMean +
                          (size_t)(mt * 16 + ln16) * (LDS_STRIDE * 2) + ks * 64 + lq * 16);

    const int rowbase = blockIdx.x * 64;
#pragma unroll 2
    for (int nt = 0; nt < 12; ++nt) {
      const int col = w * 192 + nt * 16 + ln16;
      const unsigned short* bp = W2 + (size_t)col * 128 + lq * 8;
      bf16x8 bfrag[4];
#pragma unroll
      for (int ks = 0; ks < 4; ++ks)
        bfrag[ks] = *(const bf16x8*)(bp + ks * 32);

      floatx4 acc[4];
#pragma unroll
      for (int mt = 0; mt < 4; ++mt) acc[mt] = (floatx4){0.f, 0.f, 0.f, 0.f};
#pragma unroll
      for (int ks = 0; ks < 4; ++ks)
#pragma unroll
        for (int mt = 0; mt < 4; ++mt)
          acc[mt] = __builtin_amdgcn_mfma_f32_16x16x32_bf16(afrag[mt][ks], bfrag[ks], acc[mt], 0, 0, 0);

      const float bb = b2[col];
#pragma unroll
      for (int mt = 0; mt < 4; ++mt) {
        const int r0 = rowbase + mt * 16 + lq * 4;   // D: row=(lane>>4)*4+reg, col=lane&15
#pragma unroll
        for (int r = 0; r < 4; ++r)
          out[(size_t)(r0 + r) * 768 + col] = acc[mt][r] + bb;
      }
    }
  }
}

extern "C" void kernel_launch(void* const* d_in, const int* in_sizes, int n_in,
                              void* d_out, int out_size, void* d_ws, size_t ws_size,
                              hipStream_t stream) {
  const int*   dev_ids = (const int*)d_in[0];
  const int*   pse_ids = (const int*)d_in[1];
  const int*   att_ids = (const int*)d_in[2];
  const int*   unt_ids = (const int*)d_in[3];
  const float* values  = (const float*)d_in[4];
  const int*   mask    = (const int*)d_in[5];
  const float* dev_t   = (const float*)d_in[6];
  const float* pse_t   = (const float*)d_in[7];
  const float* att_t   = (const float*)d_in[8];
  const float* unt_t   = (const float*)d_in[9];
  const float* val_w   = (const float*)d_in[10];
  const float* val_b   = (const float*)d_in[11];
  const float* ipw     = (const float*)d_in[12];
  const float* ipb     = (const float*)d_in[13];
  const float* opw     = (const float*)d_in[14];
  const float* opb     = (const float*)d_in[15];
  const float* out_w   = (const float*)d_in[16];
  const float* out_b   = (const float*)d_in[17];
  float* out = (float*)d_out;

  const int N = in_sizes[0];

  // workspace layout (float units):
  // proj 54528 | b2 768 | W2(bf16) 24576 | D 80656 | E 568 | F 568 | G 4 | PvB(bf16) 9152
  float* proj = (float*)d_ws;
  float* b2   = proj + 54528;
  unsigned short* W2 = (unsigned short*)(b2 + 768);
  float* D = (float*)(W2 + 768 * 128);
  float* E = D + 142 * 142 * 4;
  float* F = E + 142 * 4;
  float* G = F + 142 * 4;
  unsigned short* PvB = (unsigned short*)(G + 4);   // byte offset 646672, 16B aligned

  k_proj_tables<<<142, 384, 0, stream>>>(dev_t, pse_t, att_t, unt_t, val_w, val_b, ipw, proj);
  k_fuse_w2<<<768, 128, 0, stream>>>(out_w, opw, opb, out_b, W2, b2);
  k_dots<<<142, 256, 0, stream>>>(proj, ipb, D, E, F, G, PvB);
  k_main<<<N / 64, 256, 0, stream>>>(dev_ids, pse_ids, att_ids, unt_ids, values, mask,
                                     D, E, F, G, PvB, W2, b2, out);
  (void)out_size; (void)ws_size; (void)n_in;
}